// Round 5
// baseline (360.259 us; speedup 1.0000x reference)
//
#include <hip/hip_runtime.h>

#define N_TOK 16384
#define DIM 2048
#define KCLS 64
#define JRANGES 32
#define RANGE 512   // N_TOK / JRANGES
#define GRP 8       // classes per block group
#define NGRP 8      // KCLS / GRP
#define CH 8        // tokens per chunk
#define NCH (RANGE / CH)
#define EPS 1e-8f

typedef short bf16x8 __attribute__((ext_vector_type(8)));
typedef float f32x4 __attribute__((ext_vector_type(4)));

// fp32 -> bf16 RNE, branchless
__device__ __forceinline__ short f2bf(float f) {
    unsigned u = __float_as_uint(f);
    u += 0x7fffu + ((u >> 16) & 1u);
    return (short)(u >> 16);
}

// ---------------------------------------------------------------------------
// Kernel 0: sniff labels dtype (int64 vs int32) per block, normalize to int32.
// int32 random labels in [0,64) make all-(hi==0) over 256 samples impossible.
__global__ __launch_bounds__(256) void fix_labels_kernel(
    const int* __restrict__ raw, int* __restrict__ lab) {
    __shared__ int not64;
    int t = threadIdx.x, b = blockIdx.x;
    if (t == 0) not64 = 0;
    __syncthreads();
    int n0 = b * 256 + t;
    int lo = raw[2 * n0], hi = raw[2 * n0 + 1];
    if (hi != 0 || lo < 0 || lo >= KCLS) atomicOr(&not64, 1);
    __syncthreads();
    lab[n0] = not64 ? raw[n0] : raw[2 * n0];
}

// ---------------------------------------------------------------------------
// Kernel 1: per-(range, class) partial sum of class-k token vectors.
__global__ __launch_bounds__(256) void partials_kernel(
    const float* __restrict__ x, const int* __restrict__ lab,
    float* __restrict__ spart, int* __restrict__ cnt_range) {
    int bid = blockIdx.x;
    int k = bid & 63, j = bid >> 6;
    int t = threadIdx.x;
    __shared__ int ll[RANGE];
    __shared__ short ml[RANGE];
    __shared__ int nm_s;
    for (int i = t; i < RANGE; i += 256) ll[i] = lab[j * RANGE + i];
    __syncthreads();
    if (t == 0) {
        int nm = 0;
        for (int i = 0; i < RANGE; i++)
            if (ll[i] == k) ml[nm++] = (short)i;
        nm_s = nm;
        cnt_range[j * KCLS + k] = nm;
    }
    __syncthreads();
    int nm = nm_s;
    float4 a = {0, 0, 0, 0}, b4 = {0, 0, 0, 0};
    for (int m = 0; m < nm; m++) {
        const float* r = x + (size_t)(j * RANGE + (int)ml[m]) * DIM;
        float4 xa = *(const float4*)(r + t * 4);
        float4 xb = *(const float4*)(r + 1024 + t * 4);
        a.x += xa.x; a.y += xa.y; a.z += xa.z; a.w += xa.w;
        b4.x += xb.x; b4.y += xb.y; b4.z += xb.z; b4.w += xb.w;
    }
    float* dst = spart + ((size_t)j * KCLS + k) * DIM;
    *(float4*)(dst + t * 4) = a;
    *(float4*)(dst + 1024 + t * 4) = b4;
}

// ---------------------------------------------------------------------------
// Kernel 2: in-place exclusive scan over ranges -> boundary snapshots.
__global__ __launch_bounds__(256) void scan_kernel(
    const float* __restrict__ avgs, float* __restrict__ spart,
    const int* __restrict__ cnt_range, int* __restrict__ cnt_before) {
    int t = blockIdx.x * 256 + threadIdx.x;  // 32768 threads
    int k = t >> 9;
    int d4 = t & 511;
    int d = d4 * 4;
    float4 run = {0, 0, 0, 0};
    int cb = 0;
    float4 init = *(const float4*)(avgs + (size_t)k * DIM + d);
    for (int j = 0; j < JRANGES; j++) {
        size_t idx = ((size_t)j * KCLS + k) * DIM + d;
        float4 part = *(const float4*)(spart + idx);
        float4 w = (cb == 0) ? init : run;
        *(float4*)(spart + idx) = w;
        if (d4 == 0) cnt_before[j * KCLS + k] = cb;
        run.x += part.x; run.y += part.y; run.z += part.z; run.w += part.w;
        cb += cnt_range[j * KCLS + k];
    }
}

// ---------------------------------------------------------------------------
// Kernel 3 (v4): MFMA main kernel.
// Per 8-token chunk: D = X·S^T and Gram G = X·X^T via mfma_f32_16x16x32_bf16
// (8 waves split K=2048 into 256-slices; LDS reduce). A tiny scalar pass on
// the 16x16 Dm/Gm reconstructs exact sequential semantics:
//   dot(t,c) = [not-replaced]*Dm[t][c] + sum_{events e<t of c} Gm[t][e]
//   rd_e analogous; n2 evolves by 2*rd+G[e][e]; ||x_t||^2 = G[t][t].
// Prototypes: exact fp32 prefix sums in registers (64/wave K-slice), mirrored
// to bf16 LDS (XOR-swizzled) for MFMA. Token chunks: fp32 LDS (for exact
// event updates) + bf16 LDS (for MFMA), reg-staged one chunk ahead.
__global__ __launch_bounds__(512) void main_kernel(
    const float* __restrict__ x, const int* __restrict__ lab,
    const float* __restrict__ snap, const int* __restrict__ cnt_before,
    float* __restrict__ out) {
    __shared__ float Xf[CH][DIM];       // 64 KB fp32 tokens (current chunk)
    __shared__ short Xb[CH * DIM];      // 32 KB bf16 tokens (swizzled)
    __shared__ short Sb[GRP * DIM];     // 32 KB bf16 protos (swizzled)
    __shared__ float RED[8 * 512];      // 16 KB MFMA partial reduce
    __shared__ float Dm[16][17];
    __shared__ float Gm[16][17];
    __shared__ float n2_pre[GRP];
    __shared__ float rdv[CH];
    __shared__ int vflag[GRP];
    __shared__ float n2p[8][GRP];
    __shared__ unsigned char lbl[RANGE];

    int bid = blockIdx.x;
    int g = bid >> 5, j = bid & 31;   // bid%8 == j%8 -> same-range blocks share XCD L2
    int g8 = g * GRP;
    int start = j * RANGE;
    int t = threadIdx.x;
    int lane = t & 63, w = t >> 6;
    int c = lane & 7;        // class slice held by this lane (S regs / B-frag col)
    int khi = lane >> 4;     // k-subgroup 0..3
    int dup = (lane >> 3) & 1;

    // ---- prologue ----
    for (int i = t; i < RANGE; i += 512) lbl[i] = (unsigned char)lab[start + i];

    // stage chunk 0 into regs (wave w stages token w)
    float4 R[8];
    {
        const float* src = x + (size_t)(start + w) * DIM;
#pragma unroll
        for (int it = 0; it < 8; it++) R[it] = *(const float4*)(src + it * 256 + lane * 4);
    }

    // S regs: Sr[s] = S[c][w*256 + s*32 + khi*8 .. +7]  (lanes L and L^8 duplicate)
    float4 Sr[8][2];
    {
        const float* sp = snap + ((size_t)(j * KCLS + g8 + c)) * DIM + w * 256 + khi * 8;
#pragma unroll
        for (int s = 0; s < 8; s++) {
            Sr[s][0] = *(const float4*)(sp + s * 32);
            Sr[s][1] = *(const float4*)(sp + s * 32 + 4);
        }
    }
    // initial ||S||^2 per class
    float pn = 0.f;
#pragma unroll
    for (int s = 0; s < 8; s++) {
#pragma unroll
        for (int h = 0; h < 2; h++) {
            float4 v = Sr[s][h];
            pn = fmaf(v.x, v.x, pn); pn = fmaf(v.y, v.y, pn);
            pn = fmaf(v.z, v.z, pn); pn = fmaf(v.w, v.w, pn);
        }
    }
    if (dup) pn = 0.f;
    pn += __shfl_xor(pn, 8, 64);
    pn += __shfl_xor(pn, 16, 64);
    pn += __shfl_xor(pn, 32, 64);
    if (lane < 8) n2p[w][lane] = pn;
    if (t < GRP) vflag[t] = (cnt_before[j * KCLS + g8 + t] == 0) ? 1 : 0;

    // bf16 proto mirror (swizzled); dup lanes masked
    if (!dup) {
#pragma unroll
        for (int s = 0; s < 8; s++) {
            int k0 = w * 256 + s * 32 + khi * 8;
            bf16x8 hb;
            hb[0] = f2bf(Sr[s][0].x); hb[1] = f2bf(Sr[s][0].y);
            hb[2] = f2bf(Sr[s][0].z); hb[3] = f2bf(Sr[s][0].w);
            hb[4] = f2bf(Sr[s][1].x); hb[5] = f2bf(Sr[s][1].y);
            hb[6] = f2bf(Sr[s][1].z); hb[7] = f2bf(Sr[s][1].w);
            *(bf16x8*)&Sb[(c << 11) | (k0 ^ (c << 3))] = hb;
        }
    }
    // write chunk 0 (fp32 + swizzled bf16)
#pragma unroll
    for (int it = 0; it < 8; it++) *(float4*)&Xf[w][it * 256 + lane * 4] = R[it];
#pragma unroll
    for (int it = 0; it < 8; it++) {
        short4 hv = make_short4(f2bf(R[it].x), f2bf(R[it].y), f2bf(R[it].z), f2bf(R[it].w));
        int e0 = it * 256 + lane * 4;
        *(short4*)&Xb[(w << 11) | (e0 ^ ((w & 7) << 3))] = hv;
    }
    __syncthreads();
    if (t < GRP)
        n2_pre[t] = n2p[0][t] + n2p[1][t] + n2p[2][t] + n2p[3][t] +
                    n2p[4][t] + n2p[5][t] + n2p[6][t] + n2p[7][t];
    __syncthreads();

    // ---- chunk loop ----
    for (int ch = 0; ch < NCH; ch++) {
        int base = ch * CH;
        // Phase A: issue next-chunk loads + MFMA GEMM over this wave's K-slice
        if (ch + 1 < NCH) {
            const float* src = x + (size_t)(start + (ch + 1) * CH + w) * DIM;
#pragma unroll
            for (int it = 0; it < 8; it++)
                R[it] = *(const float4*)(src + it * 256 + lane * 4);
        }
        f32x4 accD = {0.f, 0.f, 0.f, 0.f}, accG = {0.f, 0.f, 0.f, 0.f};
        {
            int arow = lane & 7;          // token row (rows 8-15 duplicate)
            int aswz = arow << 3;
#pragma unroll
            for (int s = 0; s < 8; s++) {
                int k0 = w * 256 + s * 32 + khi * 8;
                bf16x8 a = *(bf16x8*)&Xb[(arow << 11) | (k0 ^ aswz)];
                bf16x8 bfr = *(bf16x8*)&Sb[(c << 11) | (k0 ^ (c << 3))];
                accD = __builtin_amdgcn_mfma_f32_16x16x32_bf16(a, bfr, accD, 0, 0, 0);
                accG = __builtin_amdgcn_mfma_f32_16x16x32_bf16(a, a, accG, 0, 0, 0);
            }
        }
#pragma unroll
        for (int r = 0; r < 4; r++) {
            RED[w * 512 + r * 64 + lane] = accD[r];
            RED[w * 512 + 256 + r * 64 + lane] = accG[r];
        }
        __syncthreads();  // B1

        // Phase B: cross-wave reduce -> Dm/Gm
        {
            float v = 0.f;
#pragma unroll
            for (int ww = 0; ww < 8; ww++) v += RED[ww * 512 + t];
            int mat = t >> 8, r = (t >> 6) & 3, l = t & 63;
            int row = ((l >> 4) << 2) + r, col = l & 15;
            if (mat == 0) Dm[row][col] = v; else Gm[row][col] = v;
        }
        __syncthreads();  // B2

        // Phase C: wave0 computes per-event raw dots rd_e; all waves update S
        if (t < 64) {
            int e = t >> 3, cc = t & 7;
            if ((int)lbl[base + e] == g8 + cc) {
                int vg = vflag[cc];
                bool seen = false;
                float sum = 0.f;
                for (int e2 = 0; e2 < e; e2++)
                    if ((int)lbl[base + e2] == g8 + cc) { seen = true; sum += Gm[e][e2]; }
                rdv[e] = ((vg && seen) ? 0.f : Dm[e][cc]) + sum;
            }
        }
        {
            unsigned seen = 0;
#pragma unroll 1
            for (int e = 0; e < CH; e++) {
                int lb = lbl[base + e];
                if ((lb >> 3) != g) continue;
                int ce = lb & 7;
                bool first = !((seen >> ce) & 1u);
                seen |= 1u << ce;
                bool rep = (vflag[ce] != 0) && first;
                if (c == ce) {
                    const float* xr = &Xf[e][w * 256 + khi * 8];
#pragma unroll
                    for (int s = 0; s < 8; s++) {
                        float4 xa = *(const float4*)(xr + s * 32);
                        float4 xb = *(const float4*)(xr + s * 32 + 4);
                        if (rep) { Sr[s][0] = xa; Sr[s][1] = xb; }
                        else {
                            Sr[s][0].x += xa.x; Sr[s][0].y += xa.y;
                            Sr[s][0].z += xa.z; Sr[s][0].w += xa.w;
                            Sr[s][1].x += xb.x; Sr[s][1].y += xb.y;
                            Sr[s][1].z += xb.z; Sr[s][1].w += xb.w;
                        }
                    }
                    if (!dup) {
#pragma unroll
                        for (int s = 0; s < 8; s++) {
                            int k0 = w * 256 + s * 32 + khi * 8;
                            bf16x8 hb;
                            hb[0] = f2bf(Sr[s][0].x); hb[1] = f2bf(Sr[s][0].y);
                            hb[2] = f2bf(Sr[s][0].z); hb[3] = f2bf(Sr[s][0].w);
                            hb[4] = f2bf(Sr[s][1].x); hb[5] = f2bf(Sr[s][1].y);
                            hb[6] = f2bf(Sr[s][1].z); hb[7] = f2bf(Sr[s][1].w);
                            *(bf16x8*)&Sb[(ce << 11) | (k0 ^ (ce << 3))] = hb;
                        }
                    }
                }
            }
        }
        __syncthreads();  // B3

        // Phase D: wave0 sims + state update; all waves write next-chunk staging
        if (t < 64) {
            int tok = t >> 3, cc = t & 7;
            float n2v = n2_pre[cc];
            int vg = vflag[cc];
            float dsum = 0.f;
            bool any_ev = false;
            for (int e = 0; e < CH; e++) {
                if ((int)lbl[base + e] != g8 + cc) continue;
                if (e < tok) {
                    if (vg && !any_ev) n2v = Gm[e][e];
                    else n2v += 2.f * rdv[e] + Gm[e][e];
                    dsum += Gm[tok][e];
                    any_ev = true;
                }
            }
            float dot = (vg && any_ev) ? dsum : (Dm[tok][cc] + dsum);
            float na = fmaxf(sqrtf(n2v), EPS);
            float nv = fmaxf(sqrtf(Gm[tok][tok]), EPS);
            out[(size_t)(start + base + tok) * KCLS + g8 + cc] = dot / (na * nv);
            if (tok == 0) {  // end-of-chunk class state
                float n2f = n2_pre[cc];
                bool anyf = false;
                for (int e = 0; e < CH; e++) {
                    if ((int)lbl[base + e] != g8 + cc) continue;
                    if (vg && !anyf) n2f = Gm[e][e];
                    else n2f += 2.f * rdv[e] + Gm[e][e];
                    anyf = true;
                }
                if (anyf) { n2_pre[cc] = n2f; vflag[cc] = 0; }
            }
        }
        if (ch + 1 < NCH) {
#pragma unroll
            for (int it = 0; it < 8; it++)
                *(float4*)&Xf[w][it * 256 + lane * 4] = R[it];
#pragma unroll
            for (int it = 0; it < 8; it++) {
                short4 hv = make_short4(f2bf(R[it].x), f2bf(R[it].y),
                                        f2bf(R[it].z), f2bf(R[it].w));
                int e0 = it * 256 + lane * 4;
                *(short4*)&Xb[(w << 11) | (e0 ^ ((w & 7) << 3))] = hv;
            }
        }
        __syncthreads();  // B4
    }
}

// ---------------------------------------------------------------------------
extern "C" void kernel_launch(void* const* d_in, const int* in_sizes, int n_in,
                              void* d_out, int out_size, void* d_ws, size_t ws_size,
                              hipStream_t stream) {
    const float* inputs = (const float*)d_in[0];
    const float* class_avgs = (const float*)d_in[1];
    const int* labels_raw = (const int*)d_in[2];
    float* out = (float*)d_out;
    char* ws = (char*)d_ws;

    size_t off = 0;
    int* lab = (int*)(ws + off);        off += (size_t)N_TOK * 4;
    int* cnt_range = (int*)(ws + off);  off += (size_t)JRANGES * KCLS * 4;
    int* cnt_before = (int*)(ws + off); off += (size_t)JRANGES * KCLS * 4;
    off = (off + 255) & ~(size_t)255;
    float* spart = (float*)(ws + off);  // JRANGES*KCLS*DIM floats = 16 MB

    fix_labels_kernel<<<N_TOK / 256, 256, 0, stream>>>(labels_raw, lab);
    partials_kernel<<<JRANGES * KCLS, 256, 0, stream>>>(inputs, lab, spart, cnt_range);
    scan_kernel<<<(KCLS * (DIM / 4)) / 256, 256, 0, stream>>>(class_avgs, spart,
                                                              cnt_range, cnt_before);
    main_kernel<<<NGRP * JRANGES, 512, 0, stream>>>(inputs, lab, spart, cnt_before, out);
}